// Round 5
// baseline (201.010 us; speedup 1.0000x reference)
//
#include <hip/hip_runtime.h>
#include <stdint.h>

// Problem constants (fixed shapes from reference)
#define M_ROWS 6272   // 32*196
#define K_DIM  768
#define N_DIM  3072
#define NITER (K_DIM / 32)   // 24 K-steps of 32

#define X_CHUNKS (M_ROWS * K_DIM / 8)   // 602112
#define W_CHUNKS (N_DIM * K_DIM / 8)    // 294912
#define X_BLOCKS (X_CHUNKS / 256)       // 2352
#define W_BLOCKS (W_CHUNKS / 256)       // 1152

typedef unsigned short u16;
typedef __attribute__((ext_vector_type(8))) __bf16 bf16x8;
typedef __attribute__((ext_vector_type(4))) float f32x4;

__device__ __forceinline__ u16 f32_to_bf16(float f) {
    unsigned u = __float_as_uint(f);
    unsigned r = 0x7FFFu + ((u >> 16) & 1u);
    return (u16)((u + r) >> 16);
}

__device__ __forceinline__ unsigned pack2(float a, float b) {
    return (unsigned)f32_to_bf16(a) | ((unsigned)f32_to_bf16(b) << 16);
}

// Fused prep: blocks [0, X_BLOCKS) cast x fp32->bf16;
// blocks [X_BLOCKS, X_BLOCKS+W_BLOCKS) expand block-circulant W to bf16.
__global__ void prep_kernel(const float* __restrict__ x, const float* __restrict__ w,
                            u16* __restrict__ xb, u16* __restrict__ wb) {
    int b = blockIdx.x;
    if (b < X_BLOCKS) {
        int idx = b * 256 + threadIdx.x;
        const float4* xp = (const float4*)x + (size_t)idx * 2;
        float4 a = xp[0], c = xp[1];
        uint4 v;
        v.x = pack2(a.x, a.y);
        v.y = pack2(a.z, a.w);
        v.z = pack2(c.x, c.y);
        v.w = pack2(c.z, c.w);
        ((uint4*)xb)[idx] = v;
    } else {
        int idx = (b - X_BLOCKS) * 256 + threadIdx.x;
        int n    = idx / 96;          // output row [0,3072)
        int kc   = idx - n * 96;      // 8-elem chunk along K
        int kblk = n / 768;           // 0..3
        int o    = n - kblk * 768;    // 0..767
        int j    = kc / 24;           // 0..3
        int c8   = kc - j * 24;       // 0..23
        int i    = (kblk - j) & 3;    // (kblk - j) mod 4
        const float* src = w + (((size_t)i * 768 + o) * 192 + c8 * 8);
        float4 a = ((const float4*)src)[0];
        float4 c = ((const float4*)src)[1];
        uint4 v;
        v.x = pack2(a.x, a.y);
        v.y = pack2(a.z, a.w);
        v.z = pack2(c.x, c.y);
        v.w = pack2(c.z, c.w);
        ((uint4*)wb)[idx] = v;
    }
}

// C[m,n] = sum_k A[m,k]*B[n,k] + bias[n]; A,B bf16 row-major K-contig, C fp32.
//
// LDS-FREE, BARRIER-FREE design (R5). Both MFMA operand fragments for
// 16x16x32_bf16 are directly loadable from row-major K-contig global memory:
//   a-frag: lane16 = row, quad*8 = k-chunk -> global_load_dwordx4 at
//           A[(row)*K + k0 + quad*8], 16B aligned, 64B segments.
//   b-frag: identical pattern on B (BT layout).
// Each wave owns an independent 64x64 output tile (4x4 of 16x16), with a
// 1-deep register prefetch of the next K-step's 8 fragments. No LDS round
// trip, no __syncthreads -> no convoy: waves slip freely, compiler keeps
// loads in flight with fine-grained vmcnt (the R1-R4 50us plateau was the
// block-synchronous barrier convoy).
// Block = 2x2 waves (128x128 region) so co-scheduled waves share A/B strips
// via L1. VGPR ~140 -> 3 waves/SIMD, no LDS occupancy cap.
__global__ __launch_bounds__(256) void gemm_bt(
    const u16* __restrict__ A,    // [M_ROWS, K_DIM] bf16
    const u16* __restrict__ B,    // [N_DIM,  K_DIM] bf16
    const float* __restrict__ bias,
    float* __restrict__ C)
{
    const int tid    = threadIdx.x;
    const int wave   = tid >> 6;
    const int lane   = tid & 63;
    const int lane16 = lane & 15;
    const int quad   = lane >> 4;
    const int wr     = wave >> 1;   // 0..1
    const int wc     = wave & 1;    // 0..1

    const int rowBase = blockIdx.y * 128 + wr * 64;
    const int colBase = blockIdx.x * 128 + wc * 64;

    // per-fragment global base pointers (k advances via +64B steps)
    const u16* ap[4];
    const u16* bp[4];
#pragma unroll
    for (int i = 0; i < 4; ++i)
        ap[i] = A + (size_t)(rowBase + i * 16 + lane16) * K_DIM + quad * 8;
#pragma unroll
    for (int j = 0; j < 4; ++j)
        bp[j] = B + (size_t)(colBase + j * 16 + lane16) * K_DIM + quad * 8;

    f32x4 acc[4][4] = {};

    bf16x8 a0[4], b0[4], a1[4], b1[4];
#pragma unroll
    for (int i = 0; i < 4; ++i) a0[i] = *(const bf16x8*)(ap[i]);
#pragma unroll
    for (int j = 0; j < 4; ++j) b0[j] = *(const bf16x8*)(bp[j]);

#pragma unroll 2
    for (int it = 0; it < NITER; ++it) {
        // prefetch next K-step into the alternate register set
        if (it + 1 < NITER) {
            const int k = (it + 1) * 32;
#pragma unroll
            for (int i = 0; i < 4; ++i) a1[i] = *(const bf16x8*)(ap[i] + k);
#pragma unroll
            for (int j = 0; j < 4; ++j) b1[j] = *(const bf16x8*)(bp[j] + k);
        }
#pragma unroll
        for (int i = 0; i < 4; ++i)
#pragma unroll
            for (int j = 0; j < 4; ++j)
                acc[i][j] = __builtin_amdgcn_mfma_f32_16x16x32_bf16(
                    a0[i], b0[j], acc[i][j], 0, 0, 0);
        // rotate
#pragma unroll
        for (int i = 0; i < 4; ++i) { a0[i] = a1[i]; b0[i] = b1[i]; }
    }

    // epilogue: C[row][col] = acc + bias[col]
    float bv[4];
#pragma unroll
    for (int j = 0; j < 4; ++j)
        bv[j] = bias[colBase + j * 16 + lane16];
#pragma unroll
    for (int i = 0; i < 4; ++i) {
        int row0 = rowBase + i * 16 + quad * 4;
#pragma unroll
        for (int r = 0; r < 4; ++r) {
            float* cp = C + (size_t)(row0 + r) * N_DIM + colBase + lane16;
#pragma unroll
            for (int j = 0; j < 4; ++j)
                cp[j * 16] = acc[i][j][r] + bv[j];
        }
    }
}

extern "C" void kernel_launch(void* const* d_in, const int* in_sizes, int n_in,
                              void* d_out, int out_size, void* d_ws, size_t ws_size,
                              hipStream_t stream) {
    const float* x    = (const float*)d_in[0];
    const float* w    = (const float*)d_in[1];
    const float* bias = (const float*)d_in[2];
    float* out = (float*)d_out;

    u16* xb = (u16*)d_ws;                                       // 9,633,792 B
    u16* wb = (u16*)((char*)d_ws + (size_t)M_ROWS * K_DIM * 2); // +4,718,592 B

    hipLaunchKernelGGL(prep_kernel, dim3(X_BLOCKS + W_BLOCKS), dim3(256),
                       0, stream, x, w, xb, wb);
    hipLaunchKernelGGL(gemm_bt, dim3(N_DIM / 128, M_ROWS / 128), dim3(256),
                       0, stream, xb, wb, bias, out);
}

// Round 6
// 159.027 us; speedup vs baseline: 1.2640x; 1.2640x over previous
//
#include <hip/hip_runtime.h>
#include <stdint.h>

// Problem constants (fixed shapes from reference)
#define M_ROWS 6272   // 32*196
#define K_DIM  768
#define N_DIM  3072
#define BM 128
#define BN 128
#define BK 32
#define NITER (K_DIM / BK)   // 24

#define X_CHUNKS (M_ROWS * K_DIM / 8)   // 602112
#define W_CHUNKS (N_DIM * K_DIM / 8)    // 294912
#define X_BLOCKS (X_CHUNKS / 256)       // 2352
#define W_BLOCKS (W_CHUNKS / 256)       // 1152

typedef unsigned short u16;
typedef __attribute__((ext_vector_type(8))) __bf16 bf16x8;
typedef __attribute__((ext_vector_type(4))) float f32x4;

__device__ __forceinline__ u16 f32_to_bf16(float f) {
    unsigned u = __float_as_uint(f);
    unsigned r = 0x7FFFu + ((u >> 16) & 1u);
    return (u16)((u + r) >> 16);
}

__device__ __forceinline__ unsigned pack2(float a, float b) {
    return (unsigned)f32_to_bf16(a) | ((unsigned)f32_to_bf16(b) << 16);
}

// LDS-only barrier: drains lgkmcnt but NOT vmcnt, so prefetched global loads
// stay in flight across the barrier (R4, verified correct).
__device__ __forceinline__ void lds_barrier() {
    asm volatile("s_waitcnt lgkmcnt(0)\n\ts_barrier" ::: "memory");
}

// Fused prep: blocks [0, X_BLOCKS) cast x fp32->bf16;
// blocks [X_BLOCKS, X_BLOCKS+W_BLOCKS) expand block-circulant W to bf16.
__global__ void prep_kernel(const float* __restrict__ x, const float* __restrict__ w,
                            u16* __restrict__ xb, u16* __restrict__ wb) {
    int b = blockIdx.x;
    if (b < X_BLOCKS) {
        int idx = b * 256 + threadIdx.x;
        const float4* xp = (const float4*)x + (size_t)idx * 2;
        float4 a = xp[0], c = xp[1];
        uint4 v;
        v.x = pack2(a.x, a.y);
        v.y = pack2(a.z, a.w);
        v.z = pack2(c.x, c.y);
        v.w = pack2(c.z, c.w);
        ((uint4*)xb)[idx] = v;
    } else {
        int idx = (b - X_BLOCKS) * 256 + threadIdx.x;
        int n    = idx / 96;          // output row [0,3072)
        int kc   = idx - n * 96;      // 8-elem chunk along K
        int kblk = n / 768;           // 0..3
        int o    = n - kblk * 768;    // 0..767
        int j    = kc / 24;           // 0..3
        int c8   = kc - j * 24;       // 0..23
        int i    = (kblk - j) & 3;    // (kblk - j) mod 4
        const float* src = w + (((size_t)i * 768 + o) * 192 + c8 * 8);
        float4 a = ((const float4*)src)[0];
        float4 c = ((const float4*)src)[1];
        uint4 v;
        v.x = pack2(a.x, a.y);
        v.y = pack2(a.z, a.w);
        v.z = pack2(c.x, c.y);
        v.w = pack2(c.z, c.w);
        ((uint4*)wb)[idx] = v;
    }
}

// C[m,n] = sum_k A[m,k]*B[n,k] + bias[n]; A,B bf16 row-major K-contig, C fp32.
//
// SPLIT-PATH design (R6): R5 proved all-direct fragment loading saturates the
// vL1D return path (3.6 GB -> 121us); R3/R4 proved all-LDS saturates LDS BW
// (~900 MB reads + staging -> 50us plateau). This kernel splits the streams:
//   A-fragments: DIRECT global_load_dwordx4 (R5-verified addressing), vL1D path
//   B-fragments: LDS-staged (R3-verified swizzle, R4-verified reg-pipeline +
//                lgkm-only barrier), LDS path
// Both on-CU bandwidth pools run in parallel; totals (452 MB LDS reads, ~680 MB
// vL1D, 120 MB HBM) put HBM back as the binding constraint.
__global__ __launch_bounds__(256) void gemm_bt(
    const u16* __restrict__ A,    // [M_ROWS, K_DIM] bf16
    const u16* __restrict__ B,    // [N_DIM,  K_DIM] bf16
    const float* __restrict__ bias,
    float* __restrict__ C)
{
    __shared__ u16 Bs[2][BN * BK];   // 2 x 8 KB

    const int tid    = threadIdx.x;
    const int wave   = tid >> 6;
    const int lane   = tid & 63;
    const int lane16 = lane & 15;
    const int quad   = lane >> 4;
    const int wr     = wave >> 1;   // 0..1
    const int wc     = wave & 1;    // 0..1

    const int rowBase = blockIdx.y * BM + wr * 64;
    const int colBase = blockIdx.x * BN;

    // ---- A: direct per-fragment global pointers (R5 addressing) ----
    const u16* ap[4];
#pragma unroll
    for (int i = 0; i < 4; ++i)
        ap[i] = A + (size_t)(rowBase + i * 16 + lane16) * K_DIM + quad * 8;

    // ---- B: LDS staging (R3 swizzle) ----
    // chunk c in [0,512): col r = c>>2, lds slot = c&3, global k-slot =
    // (c&3) ^ ((r>>1)&3). 2 chunks per thread per K-step.
    const int c0 = tid;
    const int c1 = tid + 256;
    const int r0 = c0 >> 2, s0 = (c0 & 3) ^ ((r0 >> 1) & 3);
    const int r1 = c1 >> 2, s1 = (c1 & 3) ^ ((r1 >> 1) & 3);
    const uint4* Bg0 = (const uint4*)(B + (size_t)(colBase + r0) * K_DIM + s0 * 8);
    const uint4* Bg1 = (const uint4*)(B + (size_t)(colBase + r1) * K_DIM + s1 * 8);
    uint4* Bl0 = (uint4*)&Bs[0][c0 * 8];
    uint4* Bl1 = (uint4*)&Bs[0][c1 * 8];
    const int bufStride = (BN * BK) / 8;   // uint4 elements per LDS buffer
    const int kStep = BK / 8;              // uint4 per K-tile advance per row

    // read-side swizzle for b-frags
    const int swz  = (lane16 >> 1) & 3;
    const int slot = (quad ^ swz) * 8;
    int boff[4];
#pragma unroll
    for (int j = 0; j < 4; ++j)
        boff[j] = (wc * 64 + j * 16 + lane16) * BK + slot;

    f32x4 acc[4][4] = {};

    // ---- prologue ----
    // B step0 -> regs -> LDS buf0; B step1 -> regs; A step0 -> a0
    uint4 gb0 = Bg0[0], gb1 = Bg1[0];
    Bl0[0] = gb0; Bl1[0] = gb1;
    gb0 = Bg0[kStep]; gb1 = Bg1[kStep];
    bf16x8 a0[4], a1[4];
#pragma unroll
    for (int i = 0; i < 4; ++i) a0[i] = *(const bf16x8*)(ap[i]);
    lds_barrier();

#pragma unroll 2
    for (int it = 0; it < NITER - 2; ++it) {
        const int cur = it & 1, nxt = cur ^ 1;

        // prefetch A frags for it+1 (consumed next iteration)
        {
            const int k = (it + 1) * BK;
#pragma unroll
            for (int i = 0; i < 4; ++i) a1[i] = *(const bf16x8*)(ap[i] + k);
        }

        bf16x8 bfv[4];
#pragma unroll
        for (int j = 0; j < 4; ++j)
            bfv[j] = *(const bf16x8*)&Bs[cur][boff[j]];
#pragma unroll
        for (int i = 0; i < 4; ++i)
#pragma unroll
            for (int j = 0; j < 4; ++j)
                acc[i][j] = __builtin_amdgcn_mfma_f32_16x16x32_bf16(
                    a0[i], bfv[j], acc[i][j], 0, 0, 0);

        // stage B tile it+1 (in regs since last iter) into buf[nxt]
        const int o = nxt * bufStride;
        Bl0[o] = gb0; Bl1[o] = gb1;
        // issue B loads for tile it+2
        const int g = (it + 2) * kStep;
        gb0 = Bg0[g]; gb1 = Bg1[g];
        // rotate A
#pragma unroll
        for (int i = 0; i < 4; ++i) a0[i] = a1[i];
        lds_barrier();
    }

    // it = NITER-2: compute, stage last B tile, prefetch last A frags
    {
        const int cur = (NITER - 2) & 1, nxt = cur ^ 1;
        {
            const int k = (NITER - 1) * BK;
#pragma unroll
            for (int i = 0; i < 4; ++i) a1[i] = *(const bf16x8*)(ap[i] + k);
        }
        bf16x8 bfv[4];
#pragma unroll
        for (int j = 0; j < 4; ++j)
            bfv[j] = *(const bf16x8*)&Bs[cur][boff[j]];
#pragma unroll
        for (int i = 0; i < 4; ++i)
#pragma unroll
            for (int j = 0; j < 4; ++j)
                acc[i][j] = __builtin_amdgcn_mfma_f32_16x16x32_bf16(
                    a0[i], bfv[j], acc[i][j], 0, 0, 0);
        const int o = nxt * bufStride;
        Bl0[o] = gb0; Bl1[o] = gb1;
#pragma unroll
        for (int i = 0; i < 4; ++i) a0[i] = a1[i];
        lds_barrier();
    }

    // it = NITER-1: compute only
    {
        const int cur = (NITER - 1) & 1;
        bf16x8 bfv[4];
#pragma unroll
        for (int j = 0; j < 4; ++j)
            bfv[j] = *(const bf16x8*)&Bs[cur][boff[j]];
#pragma unroll
        for (int i = 0; i < 4; ++i)
#pragma unroll
            for (int j = 0; j < 4; ++j)
                acc[i][j] = __builtin_amdgcn_mfma_f32_16x16x32_bf16(
                    a0[i], bfv[j], acc[i][j], 0, 0, 0);
    }

    // epilogue: C[row][col] = acc + bias[col]
    float bv[4];
#pragma unroll
    for (int j = 0; j < 4; ++j)
        bv[j] = bias[colBase + wc * 64 + j * 16 + lane16];
#pragma unroll
    for (int i = 0; i < 4; ++i) {
        int row0 = rowBase + i * 16 + quad * 4;
#pragma unroll
        for (int r = 0; r < 4; ++r) {
            float* cp = C + (size_t)(row0 + r) * N_DIM + colBase + wc * 64 + lane16;
#pragma unroll
            for (int j = 0; j < 4; ++j)
                cp[j * 16] = acc[i][j][r] + bv[j];
        }
    }
}

extern "C" void kernel_launch(void* const* d_in, const int* in_sizes, int n_in,
                              void* d_out, int out_size, void* d_ws, size_t ws_size,
                              hipStream_t stream) {
    const float* x    = (const float*)d_in[0];
    const float* w    = (const float*)d_in[1];
    const float* bias = (const float*)d_in[2];
    float* out = (float*)d_out;

    u16* xb = (u16*)d_ws;                                       // 9,633,792 B
    u16* wb = (u16*)((char*)d_ws + (size_t)M_ROWS * K_DIM * 2); // +4,718,592 B

    hipLaunchKernelGGL(prep_kernel, dim3(X_BLOCKS + W_BLOCKS), dim3(256),
                       0, stream, x, w, xb, wb);
    hipLaunchKernelGGL(gemm_bt, dim3(N_DIM / BN, M_ROWS / BM), dim3(256),
                       0, stream, xb, wb, bias, out);
}